// Round 3
// baseline (249.365 us; speedup 1.0000x reference)
//
#include <hip/hip_runtime.h>
#include <cstdint>

// ---------------------------------------------------------------------------
// DefaultAttention: x[4,2048,1024] fp32; k=xWk^T+bk, q=xWq^T+bq, v=xWv^T+bv;
// sim = k q^T / 32 (causal tril), attn = softmax(sim), out = attn @ v (fp32).
// R14: qkv gemm256 now a 4-buffer K-32-step pipeline with COUNTED vmcnt (T4).
// R13's vmcnt(0) drained the just-issued stage every 2 phases (the guide's
// explicit anti-pattern); with a double buffer the stage->consume distance is
// structurally <=2 phases so a counted wait was impossible. 4 bufs x 32 KiB
// (128 KiB total) give: read s | landed s+1 | in-flight s+2, s+3.
// Phase s: stage step s+3 (4 dma/thr), 12 ds_read_b128, 32 MFMA, vmcnt(8)
// (waits only step s+1, staged ~2.5 phases = ~1000cy earlier), barrier.
// WAR: stage at s overwrites buf read at s-1 -- after s-1's end barrier, all
// reads done. RAW: per-wave vmcnt(8) before end barrier => cross-wave visible.
// Tail: vmcnt 8/4/0 at s=NS-3/NS-2; none at NS-1.
// scores/pv keep the R11 BK=64 dbuf structure (unchanged this round).
// ---------------------------------------------------------------------------

typedef __attribute__((ext_vector_type(8))) _Float16 f16x8;
typedef __attribute__((ext_vector_type(4))) float f32x4;

__device__ __forceinline__ unsigned short f2h(float x) {
  return __builtin_bit_cast(unsigned short, (_Float16)x);
}

// async global->LDS, 16B per lane; LDS dest = wave-uniform base + lane*16
__device__ __forceinline__ void lds_dma16(const void* g, void* l) {
  auto gp = reinterpret_cast<const __attribute__((address_space(1))) void*>(
      reinterpret_cast<uintptr_t>(g));
  auto lp = reinterpret_cast<__attribute__((address_space(3))) void*>(
      reinterpret_cast<uintptr_t>(l));
  __builtin_amdgcn_global_load_lds(gp, lp, 16, 0, 0);
}

// ---------------------------------------------------------------------------
// stage32: one K-32 step tile, 256 rows x 32 cols f16 (16 KiB), 512 threads,
// 2 dma/thread. LDS dest linear (DMA rule: uniform base + lane*16); swizzle
// via pre-swizzled global source: LDS slot s (16B) of row r holds source
// col-block s^(r&3); readers use slot (cb ^ (r&3)). Wave b128 reads cover
// 16 rows x 4 slots disjointly (XOR bijective in qq) -> conflict-free.
// ---------------------------------------------------------------------------
__device__ __forceinline__ void stage32(const unsigned short* __restrict__ G,
                                        int ld, unsigned short* lds, int tid) {
#pragma unroll
  for (int d = 0; d < 2; ++d) {
    const int u = d * 512 + tid;           // 16B-unit index, 0..1023
    const int r = u >> 2, s = u & 3;
    const int c = (s ^ (r & 3)) * 8;       // swizzled source col (ush)
    lds_dma16(G + (size_t)r * ld + c, lds + u * 8);
  }
}

// ---------------------------------------------------------------------------
// gemm256: C[256x256] = A[256 x nk] * B[256 x nk]^T, nk % 32 == 0, nk >= 128.
// 8 waves as 2M x 4N; per-wave output 128x64 (acc[8][4]).
// One phase per K-32 step: 32 MFMA, 12 ds_read_b128, 4 dma, counted vmcnt.
// ---------------------------------------------------------------------------
__device__ __forceinline__ void gemm256(
    const unsigned short* __restrict__ Ag, const unsigned short* __restrict__ Bg,
    int lda, int ldb, int nk, unsigned short* As, unsigned short* Bs,
    f32x4 (&acc)[8][4]) {
  const int tid = threadIdx.x;
  const int lane = tid & 63, wave = tid >> 6;
  const int wr = wave >> 2, wc = wave & 3;       // 2M x 4N wave grid
  const int rr = lane & 15, qq = lane >> 4;
  const int soff = (qq ^ (rr & 3)) * 8;          // swizzled 16B slot
  const int aoff = (wr * 128 + rr) * 32 + soff;  // A row wr*128 + fi*16 + rr
  const int boff = (wc * 64 + rr) * 32 + soff;   // B row wc*64  + fj*16 + rr

#pragma unroll
  for (int fi = 0; fi < 8; ++fi)
#pragma unroll
    for (int fj = 0; fj < 4; ++fj) {
      f32x4 z = {0.f, 0.f, 0.f, 0.f};
      acc[fi][fj] = z;
    }

  const int NS = nk >> 5;
  // prologue: stage steps 0,1,2 (12 dma/thread); wait step 0 (oldest 4).
  stage32(Ag, lda, As, tid);
  stage32(Bg, ldb, Bs, tid);
  stage32(Ag + 32, lda, As + 8192, tid);
  stage32(Bg + 32, ldb, Bs + 8192, tid);
  stage32(Ag + 64, lda, As + 16384, tid);
  stage32(Bg + 64, ldb, Bs + 16384, tid);
  asm volatile("s_waitcnt vmcnt(8)" ::: "memory");
  __builtin_amdgcn_s_barrier();

  for (int s = 0; s < NS; ++s) {
    // stage step s+3 into buf (s+3)&3 = (s-1)&3 (read finished at phase s-1)
    if (s + 3 < NS) {
      stage32(Ag + (size_t)(s + 3) * 32, lda, As + ((s + 3) & 3) * 8192, tid);
      stage32(Bg + (size_t)(s + 3) * 32, ldb, Bs + ((s + 3) & 3) * 8192, tid);
    }
    // register subtile: 8 A-frags + 4 B-frags from buf s&3
    const unsigned short* Ar = As + (s & 3) * 8192 + aoff;
    const unsigned short* Br = Bs + (s & 3) * 8192 + boff;
    f16x8 af[8], bf[4];
#pragma unroll
    for (int fi = 0; fi < 8; ++fi) af[fi] = *(const f16x8*)(Ar + fi * 512);
#pragma unroll
    for (int fj = 0; fj < 4; ++fj) bf[fj] = *(const f16x8*)(Br + fj * 512);
    asm volatile("s_waitcnt lgkmcnt(8)" ::: "memory");
    __builtin_amdgcn_s_barrier();
    asm volatile("s_waitcnt lgkmcnt(0)" ::: "memory");
    __builtin_amdgcn_sched_barrier(0);
    __builtin_amdgcn_s_setprio(1);
#pragma unroll
    for (int fi = 0; fi < 8; ++fi)
#pragma unroll
      for (int fj = 0; fj < 4; ++fj)
        acc[fi][fj] = __builtin_amdgcn_mfma_f32_16x16x32_f16(
            af[fi], bf[fj], acc[fi][fj], 0, 0, 0);
    __builtin_amdgcn_s_setprio(0);
    // counted drain: need step s+1 landed; keep s+2/s+3 (8 loads) in flight.
    if (s < NS - 3) {
      asm volatile("s_waitcnt vmcnt(8)" ::: "memory");
    } else if (s == NS - 3) {
      asm volatile("s_waitcnt vmcnt(4)" ::: "memory");
    } else if (s == NS - 2) {
      asm volatile("s_waitcnt vmcnt(0)" ::: "memory");
    }
    __builtin_amdgcn_s_barrier();
  }
}

// ---------------------------------------------------------------------------
// gemm128_k64 (BK=64 dbuf, 256 thr): unchanged R11 structure for scores/pv.
// ---------------------------------------------------------------------------
__device__ __forceinline__ void gemm128_k64(
    const unsigned short* __restrict__ Ag, const unsigned short* __restrict__ Bg,
    int lda, int ldb, int nk, unsigned short* As, unsigned short* Bs,
    f32x4 acc[4][4]) {
  const int tid = threadIdx.x;
  const int lane = tid & 63, wave = tid >> 6;
  const int wm = wave >> 1, wn = wave & 1;
  const int sr = lane >> 3;                     // staging row within 8-row chunk
  const int scb = ((lane & 7) ^ sr) * 8;        // swizzled source col (ush)
  const int rr = lane & 15, qq = lane >> 4;
  const int slot0 = ((qq) ^ (rr & 7)) * 8;      // k-half 0 read col
  const int slot1 = ((4 + qq) ^ (rr & 7)) * 8;  // k-half 1 read col

#pragma unroll
  for (int i = 0; i < 4; ++i)
#pragma unroll
    for (int j = 0; j < 4; ++j) {
      f32x4 z = {0.f, 0.f, 0.f, 0.f};
      acc[i][j] = z;
    }

  // prologue: stage k=0 into buf 0 (16 chunks of 8 rows; wave w: 4w..4w+3)
#pragma unroll
  for (int c = 0; c < 4; ++c) {
    int chunk = wave * 4 + c;
    int row = chunk * 8 + sr;
    lds_dma16(Ag + (size_t)row * lda + scb, As + chunk * 512);
    lds_dma16(Bg + (size_t)row * ldb + scb, Bs + chunk * 512);
  }

  int buf = 0;
  for (int k0 = 0; k0 < nk; k0 += 64) {
    __syncthreads();  // drains staging issued one compute-phase ago
    const int kn = k0 + 64;
    if (kn < nk) {
      unsigned short* An = As + (buf ^ 1) * 8192;
      unsigned short* Bn = Bs + (buf ^ 1) * 8192;
#pragma unroll
      for (int c = 0; c < 4; ++c) {
        int chunk = wave * 4 + c;
        int row = chunk * 8 + sr;
        lds_dma16(Ag + (size_t)row * lda + kn + scb, An + chunk * 512);
        lds_dma16(Bg + (size_t)row * ldb + kn + scb, Bn + chunk * 512);
      }
    }

    const unsigned short* Ar = As + buf * 8192 + (wm * 64 + rr) * 64;
    const unsigned short* Br = Bs + buf * 8192 + (wn * 64 + rr) * 64;
    {
      f16x8 af[4], bf[4];
#pragma unroll
      for (int i = 0; i < 4; ++i) af[i] = *(const f16x8*)(Ar + i * 1024 + slot0);
#pragma unroll
      for (int j = 0; j < 4; ++j) bf[j] = *(const f16x8*)(Br + j * 1024 + slot0);
#pragma unroll
      for (int i = 0; i < 4; ++i)
#pragma unroll
        for (int j = 0; j < 4; ++j)
          acc[i][j] = __builtin_amdgcn_mfma_f32_16x16x32_f16(af[i], bf[j],
                                                             acc[i][j], 0, 0, 0);
    }
    {
      f16x8 af[4], bf[4];
#pragma unroll
      for (int i = 0; i < 4; ++i) af[i] = *(const f16x8*)(Ar + i * 1024 + slot1);
#pragma unroll
      for (int j = 0; j < 4; ++j) bf[j] = *(const f16x8*)(Br + j * 1024 + slot1);
#pragma unroll
      for (int i = 0; i < 4; ++i)
#pragma unroll
        for (int j = 0; j < 4; ++j)
          acc[i][j] = __builtin_amdgcn_mfma_f32_16x16x32_f16(af[i], bf[j],
                                                             acc[i][j], 0, 0, 0);
    }
    buf ^= 1;
  }
}

// ---------------------------------------------------------------------------
// fp32 -> f16 convert: x then Wk,Wq,Wv into contiguous [xh | wh];
// last 8 blocks zero rsum (8192 floats).
// ---------------------------------------------------------------------------
__global__ void cvt_kernel(const float* __restrict__ x,
                           const float* __restrict__ w0,
                           const float* __restrict__ w1,
                           const float* __restrict__ w2,
                           unsigned short* __restrict__ dst,
                           float* __restrict__ rsum) {
  int i = blockIdx.x * 256 + threadIdx.x;
  if (i >= 2883584) {
    int z2 = i - 2883584;
    float4 z = {0.f, 0.f, 0.f, 0.f};
    ((float4*)rsum)[z2] = z;
    return;
  }
  const float* s;
  size_t si;
  if (i < 2097152) {
    s = x; si = i;
  } else {
    int j = i - 2097152;
    int z = j >> 18;
    s = (z == 0) ? w0 : ((z == 1) ? w1 : w2);
    si = j & 262143;
  }
  float4 f = ((const float4*)s)[si];
  ushort4 u;
  u.x = f2h(f.x); u.y = f2h(f.y); u.z = f2h(f.z); u.w = f2h(f.w);
  ((ushort4*)dst)[i] = u;
}

// ---------------------------------------------------------------------------
// QKV projection, 256x256 pipelined. 384 jobs, XCD-swizzled (384 = 8*48):
//   job <  256: KQ. tm=job>>3 (token tile), tn=job&7 over [Wk;Wq] (2048 rows)
//               -> kh (tn<4) or qh (tn>=4), + bias per col.
//   job >= 256: V.  dt=(job-256)>>5 (d tile), tt=(job-256)&31 (token tile)
//               C[d,t] = Wv[d-tile] . xh[t-slab]^T -> vT[b][d][t] + bv per row.
// ---------------------------------------------------------------------------
__global__ __launch_bounds__(512, 2) void qkv256_kernel(
    const unsigned short* __restrict__ xh, const unsigned short* __restrict__ wh,
    const float* __restrict__ bk, const float* __restrict__ bq,
    const float* __restrict__ bv, unsigned short* __restrict__ kh,
    unsigned short* __restrict__ qh, unsigned short* __restrict__ vT) {
  __shared__ unsigned short As[32768], Bs[32768];  // 4 bufs x 16 KiB each side
  const int job = (blockIdx.x & 7) * 48 + (blockIdx.x >> 3);

  const unsigned short* Ag;
  const unsigned short* Bg;
  if (job < 256) {
    const int tm = job >> 3, tn = job & 7;
    Ag = xh + (size_t)tm * 256 * 1024;
    Bg = wh + (size_t)tn * 256 * 1024;
  } else {
    const int j = job - 256;
    const int dt = j >> 5, tt = j & 31;
    Ag = wh + 2097152 + (size_t)dt * 256 * 1024;
    Bg = xh + (size_t)tt * 256 * 1024;
  }

  f32x4 acc[8][4];
  gemm256(Ag, Bg, 1024, 1024, 1024, As, Bs, acc);

  const int tid = threadIdx.x;
  const int lane = tid & 63, wave = tid >> 6;
  const int wr = wave >> 2, wc = wave & 3, rr = lane & 15, qq = lane >> 4;

  if (job < 256) {
    const int tm = job >> 3, tn = job & 7;
    const bool isq = tn >= 4;
    unsigned short* dst = isq ? qh : kh;
    const float* bias = isq ? bq : bk;
    const int nbase = (tn & 3) * 256;
    float bj[4];
#pragma unroll
    for (int fj = 0; fj < 4; ++fj)
      bj[fj] = bias[nbase + wc * 64 + fj * 16 + rr];
#pragma unroll
    for (int fi = 0; fi < 8; ++fi)
#pragma unroll
      for (int reg = 0; reg < 4; ++reg) {
        const int m = tm * 256 + wr * 128 + fi * 16 + qq * 4 + reg;
#pragma unroll
        for (int fj = 0; fj < 4; ++fj) {
          const int n = nbase + wc * 64 + fj * 16 + rr;
          dst[(size_t)m * 1024 + n] = f2h(acc[fi][fj][reg] + bj[fj]);
        }
      }
  } else {
    const int j = job - 256;
    const int dt = j >> 5, tt = j & 31;
#pragma unroll
    for (int fi = 0; fi < 8; ++fi) {
      const int d0 = dt * 256 + wr * 128 + fi * 16 + qq * 4;
      const float4 b4 = *(const float4*)(bv + d0);
      const float bir[4] = {b4.x, b4.y, b4.z, b4.w};
#pragma unroll
      for (int reg = 0; reg < 4; ++reg) {
        const int d = d0 + reg;
#pragma unroll
        for (int fj = 0; fj < 4; ++fj) {
          const int tg = tt * 256 + wc * 64 + fj * 16 + rr;
          const int bb = tg >> 11, t = tg & 2047;
          vT[((size_t)(bb * 1024 + d)) * 2048 + t] =
              f2h(acc[fi][fj][reg] + bir[reg]);
        }
      }
    }
  }
}

// ---------------------------------------------------------------------------
// scores: P[b,s,t] = exp(k[s].q[t]/32 - 4) for t<=s else 0  (f16), plus
// fused row-sum atomics. Triangular grid (136,4). BK=64 dbuf pipeline.
// ---------------------------------------------------------------------------
__global__ __launch_bounds__(256) void scores_kernel(
    const unsigned short* __restrict__ kh, const unsigned short* __restrict__ qh,
    unsigned short* __restrict__ P, float* __restrict__ rsum) {
  const int b = blockIdx.y;
  int idx = blockIdx.x;
  int ts = (int)((sqrtf(8.0f * idx + 1.0f) - 1.0f) * 0.5f);
  while ((ts + 1) * (ts + 2) / 2 <= idx) ++ts;
  while (ts * (ts + 1) / 2 > idx) --ts;
  const int tt = idx - ts * (ts + 1) / 2;
  __shared__ unsigned short As[2 * 128 * 64], Bs[2 * 128 * 64];

  f32x4 acc[4][4];
  gemm128_k64(kh + ((size_t)(b * 2048 + ts * 128)) * 1024,
              qh + ((size_t)(b * 2048 + tt * 128)) * 1024,
              1024, 1024, 1024, As, Bs, acc);

  const int lane = threadIdx.x & 63, wave = threadIdx.x >> 6;
  const int wm = wave >> 1, wn = wave & 1, rr = lane & 15, qq = lane >> 4;
  unsigned short* Pb = P + (size_t)b * 2048 * 2048;
  float* rs = rsum + b * 2048;
#pragma unroll
  for (int i = 0; i < 4; ++i)
#pragma unroll
    for (int reg = 0; reg < 4; ++reg) {
      int srow = ts * 128 + wm * 64 + i * 16 + qq * 4 + reg;
      float p = 0.f;
#pragma unroll
      for (int j = 0; j < 4; ++j) {
        int tcol = tt * 128 + wn * 64 + j * 16 + rr;
        float e = (tcol <= srow) ? __expf(acc[i][j][reg] * 0.03125f - 4.0f)
                                 : 0.0f;
        Pb[(size_t)srow * 2048 + tcol] = f2h(e);
        p += e;
      }
#pragma unroll
      for (int off = 1; off < 16; off <<= 1) p += __shfl_xor(p, off);
      if (rr == 0) atomicAdd(rs + srow, p);
    }
}

// ---------------------------------------------------------------------------
// pv: out[b,s,d] = (1/rsum[b,s]) * sum_t P[b,s,t] * vT[b,d,t]   (fp32 out)
// grid (8,16,4); K truncated to (ts+1)*128; y reversed (big-K first).
// BK=64 dbuf pipeline.
// ---------------------------------------------------------------------------
__global__ __launch_bounds__(256) void pv_gemm_kernel(
    const unsigned short* __restrict__ P, const unsigned short* __restrict__ vT,
    const float* __restrict__ rsum, float* __restrict__ out) {
  const int td = blockIdx.x, ts = 15 - blockIdx.y, b = blockIdx.z;
  __shared__ unsigned short As[2 * 128 * 64], Bs[2 * 128 * 64];

  f32x4 acc[4][4];
  gemm128_k64(P + ((size_t)(b * 2048 + ts * 128)) * 2048,
              vT + ((size_t)(b * 1024 + td * 128)) * 2048,
              2048, 2048, (ts + 1) * 128, As, Bs, acc);

  const int lane = threadIdx.x & 63, wave = threadIdx.x >> 6;
  const int wm = wave >> 1, wn = wave & 1, rr = lane & 15, qq = lane >> 4;
#pragma unroll
  for (int i = 0; i < 4; ++i) {
    int s0 = ts * 128 + wm * 64 + i * 16 + qq * 4;
    float4 r4 = *(const float4*)(rsum + b * 2048 + s0);
    float rv[4] = {__builtin_amdgcn_rcpf(r4.x), __builtin_amdgcn_rcpf(r4.y),
                   __builtin_amdgcn_rcpf(r4.z), __builtin_amdgcn_rcpf(r4.w)};
#pragma unroll
    for (int reg = 0; reg < 4; ++reg) {
      int srow = s0 + reg;
#pragma unroll
      for (int j = 0; j < 4; ++j) {
        int dcol = td * 128 + wn * 64 + j * 16 + rr;
        out[((size_t)(b * 2048 + srow)) * 1024 + dcol] =
            acc[i][j][reg] * rv[reg];
      }
    }
  }
}

// ---------------------------------------------------------------------------
// launch
// ---------------------------------------------------------------------------
extern "C" void kernel_launch(void* const* d_in, const int* in_sizes, int n_in,
                              void* d_out, int out_size, void* d_ws,
                              size_t ws_size, hipStream_t stream) {
  const float* x  = (const float*)d_in[0];
  const float* Wk = (const float*)d_in[1];
  const float* bk = (const float*)d_in[2];
  const float* Wq = (const float*)d_in[3];
  const float* bq = (const float*)d_in[4];
  const float* Wv = (const float*)d_in[5];
  const float* bv = (const float*)d_in[6];
  float* out = (float*)d_out;

  char* ws = (char*)d_ws;
  const size_t MB = 1ull << 20;
  // Aliased layout (86 MB + 32 KB): P overlays xh/wh (dead by scores).
  unsigned short* xh = (unsigned short*)(ws + 0);        // 16 MB  [0,16)
  unsigned short* wh = (unsigned short*)(ws + 16 * MB);  //  6 MB  [16,22)
  unsigned short* P  = (unsigned short*)(ws + 0);        // 32 MB  [0,32) alias
  unsigned short* kh = (unsigned short*)(ws + 38 * MB);  // 16 MB  [38,54)
  unsigned short* qh = (unsigned short*)(ws + 54 * MB);  // 16 MB  [54,70)
  unsigned short* vT = (unsigned short*)(ws + 70 * MB);  // 16 MB  [70,86)
  float* rsum = (float*)(ws + 86 * MB);                  // 32 KB

  // 1) converts (x + 3 W) + rsum zero-init (last 8 blocks)
  cvt_kernel<<<11272, 256, 0, stream>>>(x, Wk, Wq, Wv, xh, rsum);
  // 2) QKV projections, 256^2 4-buffer counted-vmcnt; V operand-swapped -> vT
  qkv256_kernel<<<384, 512, 0, stream>>>(xh, wh, bk, bq, bv, kh, qh, vT);
  // 3) masked exp(scores) + fused row-sum atomics (BK=64 dbuf)
  scores_kernel<<<dim3(136, 4), 256, 0, stream>>>(kh, qh, P, rsum);
  // 4) (P @ v) * (1/rsum) -> out (BK=64 dbuf)
  pv_gemm_kernel<<<dim3(8, 16, 4), 256, 0, stream>>>(P, vT, rsum, out);
}

// Round 4
// 243.463 us; speedup vs baseline: 1.0242x; 1.0242x over previous
//
#include <hip/hip_runtime.h>
#include <cstdint>

// ---------------------------------------------------------------------------
// DefaultAttention: x[4,2048,1024] fp32; k=xWk^T+bk, q=xWq^T+bq, v=xWv^T+bv;
// sim = k q^T / 32 (causal tril), attn = softmax(sim), out = attn @ v (fp32).
// R15: fixes R14's LDS bank conflicts (4.7M counted, 4 cyc/b128). With K-32
// step tiles rows are 64 B, so byte%128 = (r&1)*64 + slot*16; R14's swizzle
// slot=qq^(r&3) aliased lanes rr and rr+4 into the same window. New swizzle
// slot = qq ^ ((r>>1)&3): any 8 consecutive lanes cover all 8 distinct
// 16B-windows (full 32-bank coverage), 16-lane groups are 2-way (free).
// Pipeline unchanged from R14 (the actual T4 test, now unconfounded):
// 4 bufs x 8 KiB/side, phase s: stage step s+3 (4 dma/thr), 12 ds_read_b128,
// 32 MFMA, steady-state vmcnt(8) (waits step s+1 only, staged ~2.5 phases
// earlier; s+2/s+3 stay in flight across the barrier), tail 8/4/0.
// scores/pv keep the R11 BK=64 dbuf structure (unchanged this round).
// ---------------------------------------------------------------------------

typedef __attribute__((ext_vector_type(8))) _Float16 f16x8;
typedef __attribute__((ext_vector_type(4))) float f32x4;

__device__ __forceinline__ unsigned short f2h(float x) {
  return __builtin_bit_cast(unsigned short, (_Float16)x);
}

// async global->LDS, 16B per lane; LDS dest = wave-uniform base + lane*16
__device__ __forceinline__ void lds_dma16(const void* g, void* l) {
  auto gp = reinterpret_cast<const __attribute__((address_space(1))) void*>(
      reinterpret_cast<uintptr_t>(g));
  auto lp = reinterpret_cast<__attribute__((address_space(3))) void*>(
      reinterpret_cast<uintptr_t>(l));
  __builtin_amdgcn_global_load_lds(gp, lp, 16, 0, 0);
}

// ---------------------------------------------------------------------------
// stage32: one K-32 step tile, 256 rows x 32 cols f16 (16 KiB), 512 threads,
// 2 dma/thread. LDS dest linear (DMA rule: uniform base + lane*16); swizzle
// via pre-swizzled global source: LDS slot s (16B) of row r holds source
// col-block s ^ ((r>>1)&3); readers use slot (cb ^ ((r>>1)&3)).
// Bank check: lane byte%128 = (r&1)*64 + slot*16 -> 8 consecutive lanes hit
// 8 distinct windows (32 banks), 16-lane groups 2-way (free per m136).
// ---------------------------------------------------------------------------
__device__ __forceinline__ void stage32(const unsigned short* __restrict__ G,
                                        int ld, unsigned short* lds, int tid) {
#pragma unroll
  for (int d = 0; d < 2; ++d) {
    const int u = d * 512 + tid;           // 16B-unit index, 0..1023
    const int r = u >> 2, s = u & 3;
    const int c = (s ^ ((r >> 1) & 3)) * 8;  // swizzled source col (ush)
    lds_dma16(G + (size_t)r * ld + c, lds + u * 8);
  }
}

// ---------------------------------------------------------------------------
// gemm256: C[256x256] = A[256 x nk] * B[256 x nk]^T, nk % 32 == 0, nk >= 128.
// 8 waves as 2M x 4N; per-wave output 128x64 (acc[8][4]).
// One phase per K-32 step: 32 MFMA, 12 ds_read_b128, 4 dma, counted vmcnt.
// ---------------------------------------------------------------------------
__device__ __forceinline__ void gemm256(
    const unsigned short* __restrict__ Ag, const unsigned short* __restrict__ Bg,
    int lda, int ldb, int nk, unsigned short* As, unsigned short* Bs,
    f32x4 (&acc)[8][4]) {
  const int tid = threadIdx.x;
  const int lane = tid & 63, wave = tid >> 6;
  const int wr = wave >> 2, wc = wave & 3;       // 2M x 4N wave grid
  const int rr = lane & 15, qq = lane >> 4;
  const int soff = (qq ^ ((rr >> 1) & 3)) * 8;   // swizzled 16B slot
  const int aoff = (wr * 128 + rr) * 32 + soff;  // A row wr*128 + fi*16 + rr
  const int boff = (wc * 64 + rr) * 32 + soff;   // B row wc*64  + fj*16 + rr

#pragma unroll
  for (int fi = 0; fi < 8; ++fi)
#pragma unroll
    for (int fj = 0; fj < 4; ++fj) {
      f32x4 z = {0.f, 0.f, 0.f, 0.f};
      acc[fi][fj] = z;
    }

  const int NS = nk >> 5;
  // prologue: stage steps 0,1,2 (12 dma/thread); wait step 0 (oldest 4).
  stage32(Ag, lda, As, tid);
  stage32(Bg, ldb, Bs, tid);
  stage32(Ag + 32, lda, As + 8192, tid);
  stage32(Bg + 32, ldb, Bs + 8192, tid);
  stage32(Ag + 64, lda, As + 16384, tid);
  stage32(Bg + 64, ldb, Bs + 16384, tid);
  asm volatile("s_waitcnt vmcnt(8)" ::: "memory");
  __builtin_amdgcn_s_barrier();

  for (int s = 0; s < NS; ++s) {
    // stage step s+3 into buf (s+3)&3 = (s-1)&3 (read finished at phase s-1)
    if (s + 3 < NS) {
      stage32(Ag + (size_t)(s + 3) * 32, lda, As + ((s + 3) & 3) * 8192, tid);
      stage32(Bg + (size_t)(s + 3) * 32, ldb, Bs + ((s + 3) & 3) * 8192, tid);
    }
    // register subtile: 8 A-frags + 4 B-frags from buf s&3
    const unsigned short* Ar = As + (s & 3) * 8192 + aoff;
    const unsigned short* Br = Bs + (s & 3) * 8192 + boff;
    f16x8 af[8], bf[4];
#pragma unroll
    for (int fi = 0; fi < 8; ++fi) af[fi] = *(const f16x8*)(Ar + fi * 512);
#pragma unroll
    for (int fj = 0; fj < 4; ++fj) bf[fj] = *(const f16x8*)(Br + fj * 512);
    asm volatile("s_waitcnt lgkmcnt(8)" ::: "memory");
    __builtin_amdgcn_s_barrier();
    asm volatile("s_waitcnt lgkmcnt(0)" ::: "memory");
    __builtin_amdgcn_sched_barrier(0);
    __builtin_amdgcn_s_setprio(1);
#pragma unroll
    for (int fi = 0; fi < 8; ++fi)
#pragma unroll
      for (int fj = 0; fj < 4; ++fj)
        acc[fi][fj] = __builtin_amdgcn_mfma_f32_16x16x32_f16(
            af[fi], bf[fj], acc[fi][fj], 0, 0, 0);
    __builtin_amdgcn_s_setprio(0);
    // counted drain: need step s+1 landed; keep s+2/s+3 (8 loads) in flight.
    if (s < NS - 3) {
      asm volatile("s_waitcnt vmcnt(8)" ::: "memory");
    } else if (s == NS - 3) {
      asm volatile("s_waitcnt vmcnt(4)" ::: "memory");
    } else if (s == NS - 2) {
      asm volatile("s_waitcnt vmcnt(0)" ::: "memory");
    }
    __builtin_amdgcn_s_barrier();
  }
}

// ---------------------------------------------------------------------------
// gemm128_k64 (BK=64 dbuf, 256 thr): unchanged R11 structure for scores/pv.
// ---------------------------------------------------------------------------
__device__ __forceinline__ void gemm128_k64(
    const unsigned short* __restrict__ Ag, const unsigned short* __restrict__ Bg,
    int lda, int ldb, int nk, unsigned short* As, unsigned short* Bs,
    f32x4 acc[4][4]) {
  const int tid = threadIdx.x;
  const int lane = tid & 63, wave = tid >> 6;
  const int wm = wave >> 1, wn = wave & 1;
  const int sr = lane >> 3;                     // staging row within 8-row chunk
  const int scb = ((lane & 7) ^ sr) * 8;        // swizzled source col (ush)
  const int rr = lane & 15, qq = lane >> 4;
  const int slot0 = ((qq) ^ (rr & 7)) * 8;      // k-half 0 read col
  const int slot1 = ((4 + qq) ^ (rr & 7)) * 8;  // k-half 1 read col

#pragma unroll
  for (int i = 0; i < 4; ++i)
#pragma unroll
    for (int j = 0; j < 4; ++j) {
      f32x4 z = {0.f, 0.f, 0.f, 0.f};
      acc[i][j] = z;
    }

  // prologue: stage k=0 into buf 0 (16 chunks of 8 rows; wave w: 4w..4w+3)
#pragma unroll
  for (int c = 0; c < 4; ++c) {
    int chunk = wave * 4 + c;
    int row = chunk * 8 + sr;
    lds_dma16(Ag + (size_t)row * lda + scb, As + chunk * 512);
    lds_dma16(Bg + (size_t)row * ldb + scb, Bs + chunk * 512);
  }

  int buf = 0;
  for (int k0 = 0; k0 < nk; k0 += 64) {
    __syncthreads();  // drains staging issued one compute-phase ago
    const int kn = k0 + 64;
    if (kn < nk) {
      unsigned short* An = As + (buf ^ 1) * 8192;
      unsigned short* Bn = Bs + (buf ^ 1) * 8192;
#pragma unroll
      for (int c = 0; c < 4; ++c) {
        int chunk = wave * 4 + c;
        int row = chunk * 8 + sr;
        lds_dma16(Ag + (size_t)row * lda + kn + scb, An + chunk * 512);
        lds_dma16(Bg + (size_t)row * ldb + kn + scb, Bn + chunk * 512);
      }
    }

    const unsigned short* Ar = As + buf * 8192 + (wm * 64 + rr) * 64;
    const unsigned short* Br = Bs + buf * 8192 + (wn * 64 + rr) * 64;
    {
      f16x8 af[4], bf[4];
#pragma unroll
      for (int i = 0; i < 4; ++i) af[i] = *(const f16x8*)(Ar + i * 1024 + slot0);
#pragma unroll
      for (int j = 0; j < 4; ++j) bf[j] = *(const f16x8*)(Br + j * 1024 + slot0);
#pragma unroll
      for (int i = 0; i < 4; ++i)
#pragma unroll
        for (int j = 0; j < 4; ++j)
          acc[i][j] = __builtin_amdgcn_mfma_f32_16x16x32_f16(af[i], bf[j],
                                                             acc[i][j], 0, 0, 0);
    }
    {
      f16x8 af[4], bf[4];
#pragma unroll
      for (int i = 0; i < 4; ++i) af[i] = *(const f16x8*)(Ar + i * 1024 + slot1);
#pragma unroll
      for (int j = 0; j < 4; ++j) bf[j] = *(const f16x8*)(Br + j * 1024 + slot1);
#pragma unroll
      for (int i = 0; i < 4; ++i)
#pragma unroll
        for (int j = 0; j < 4; ++j)
          acc[i][j] = __builtin_amdgcn_mfma_f32_16x16x32_f16(af[i], bf[j],
                                                             acc[i][j], 0, 0, 0);
    }
    buf ^= 1;
  }
}

// ---------------------------------------------------------------------------
// fp32 -> f16 convert: x then Wk,Wq,Wv into contiguous [xh | wh];
// last 8 blocks zero rsum (8192 floats).
// ---------------------------------------------------------------------------
__global__ void cvt_kernel(const float* __restrict__ x,
                           const float* __restrict__ w0,
                           const float* __restrict__ w1,
                           const float* __restrict__ w2,
                           unsigned short* __restrict__ dst,
                           float* __restrict__ rsum) {
  int i = blockIdx.x * 256 + threadIdx.x;
  if (i >= 2883584) {
    int z2 = i - 2883584;
    float4 z = {0.f, 0.f, 0.f, 0.f};
    ((float4*)rsum)[z2] = z;
    return;
  }
  const float* s;
  size_t si;
  if (i < 2097152) {
    s = x; si = i;
  } else {
    int j = i - 2097152;
    int z = j >> 18;
    s = (z == 0) ? w0 : ((z == 1) ? w1 : w2);
    si = j & 262143;
  }
  float4 f = ((const float4*)s)[si];
  ushort4 u;
  u.x = f2h(f.x); u.y = f2h(f.y); u.z = f2h(f.z); u.w = f2h(f.w);
  ((ushort4*)dst)[i] = u;
}

// ---------------------------------------------------------------------------
// QKV projection, 256x256 pipelined. 384 jobs, XCD-swizzled (384 = 8*48):
//   job <  256: KQ. tm=job>>3 (token tile), tn=job&7 over [Wk;Wq] (2048 rows)
//               -> kh (tn<4) or qh (tn>=4), + bias per col.
//   job >= 256: V.  dt=(job-256)>>5 (d tile), tt=(job-256)&31 (token tile)
//               C[d,t] = Wv[d-tile] . xh[t-slab]^T -> vT[b][d][t] + bv per row.
// ---------------------------------------------------------------------------
__global__ __launch_bounds__(512, 2) void qkv256_kernel(
    const unsigned short* __restrict__ xh, const unsigned short* __restrict__ wh,
    const float* __restrict__ bk, const float* __restrict__ bq,
    const float* __restrict__ bv, unsigned short* __restrict__ kh,
    unsigned short* __restrict__ qh, unsigned short* __restrict__ vT) {
  __shared__ unsigned short As[32768], Bs[32768];  // 4 bufs x 16 KiB each side
  const int job = (blockIdx.x & 7) * 48 + (blockIdx.x >> 3);

  const unsigned short* Ag;
  const unsigned short* Bg;
  if (job < 256) {
    const int tm = job >> 3, tn = job & 7;
    Ag = xh + (size_t)tm * 256 * 1024;
    Bg = wh + (size_t)tn * 256 * 1024;
  } else {
    const int j = job - 256;
    const int dt = j >> 5, tt = j & 31;
    Ag = wh + 2097152 + (size_t)dt * 256 * 1024;
    Bg = xh + (size_t)tt * 256 * 1024;
  }

  f32x4 acc[8][4];
  gemm256(Ag, Bg, 1024, 1024, 1024, As, Bs, acc);

  const int tid = threadIdx.x;
  const int lane = tid & 63, wave = tid >> 6;
  const int wr = wave >> 2, wc = wave & 3, rr = lane & 15, qq = lane >> 4;

  if (job < 256) {
    const int tm = job >> 3, tn = job & 7;
    const bool isq = tn >= 4;
    unsigned short* dst = isq ? qh : kh;
    const float* bias = isq ? bq : bk;
    const int nbase = (tn & 3) * 256;
    float bj[4];
#pragma unroll
    for (int fj = 0; fj < 4; ++fj)
      bj[fj] = bias[nbase + wc * 64 + fj * 16 + rr];
#pragma unroll
    for (int fi = 0; fi < 8; ++fi)
#pragma unroll
      for (int reg = 0; reg < 4; ++reg) {
        const int m = tm * 256 + wr * 128 + fi * 16 + qq * 4 + reg;
#pragma unroll
        for (int fj = 0; fj < 4; ++fj) {
          const int n = nbase + wc * 64 + fj * 16 + rr;
          dst[(size_t)m * 1024 + n] = f2h(acc[fi][fj][reg] + bj[fj]);
        }
      }
  } else {
    const int j = job - 256;
    const int dt = j >> 5, tt = j & 31;
#pragma unroll
    for (int fi = 0; fi < 8; ++fi) {
      const int d0 = dt * 256 + wr * 128 + fi * 16 + qq * 4;
      const float4 b4 = *(const float4*)(bv + d0);
      const float bir[4] = {b4.x, b4.y, b4.z, b4.w};
#pragma unroll
      for (int reg = 0; reg < 4; ++reg) {
        const int d = d0 + reg;
#pragma unroll
        for (int fj = 0; fj < 4; ++fj) {
          const int tg = tt * 256 + wc * 64 + fj * 16 + rr;
          const int bb = tg >> 11, t = tg & 2047;
          vT[((size_t)(bb * 1024 + d)) * 2048 + t] =
              f2h(acc[fi][fj][reg] + bir[reg]);
        }
      }
    }
  }
}

// ---------------------------------------------------------------------------
// scores: P[b,s,t] = exp(k[s].q[t]/32 - 4) for t<=s else 0  (f16), plus
// fused row-sum atomics. Triangular grid (136,4). BK=64 dbuf pipeline.
// ---------------------------------------------------------------------------
__global__ __launch_bounds__(256) void scores_kernel(
    const unsigned short* __restrict__ kh, const unsigned short* __restrict__ qh,
    unsigned short* __restrict__ P, float* __restrict__ rsum) {
  const int b = blockIdx.y;
  int idx = blockIdx.x;
  int ts = (int)((sqrtf(8.0f * idx + 1.0f) - 1.0f) * 0.5f);
  while ((ts + 1) * (ts + 2) / 2 <= idx) ++ts;
  while (ts * (ts + 1) / 2 > idx) --ts;
  const int tt = idx - ts * (ts + 1) / 2;
  __shared__ unsigned short As[2 * 128 * 64], Bs[2 * 128 * 64];

  f32x4 acc[4][4];
  gemm128_k64(kh + ((size_t)(b * 2048 + ts * 128)) * 1024,
              qh + ((size_t)(b * 2048 + tt * 128)) * 1024,
              1024, 1024, 1024, As, Bs, acc);

  const int lane = threadIdx.x & 63, wave = threadIdx.x >> 6;
  const int wm = wave >> 1, wn = wave & 1, rr = lane & 15, qq = lane >> 4;
  unsigned short* Pb = P + (size_t)b * 2048 * 2048;
  float* rs = rsum + b * 2048;
#pragma unroll
  for (int i = 0; i < 4; ++i)
#pragma unroll
    for (int reg = 0; reg < 4; ++reg) {
      int srow = ts * 128 + wm * 64 + i * 16 + qq * 4 + reg;
      float p = 0.f;
#pragma unroll
      for (int j = 0; j < 4; ++j) {
        int tcol = tt * 128 + wn * 64 + j * 16 + rr;
        float e = (tcol <= srow) ? __expf(acc[i][j][reg] * 0.03125f - 4.0f)
                                 : 0.0f;
        Pb[(size_t)srow * 2048 + tcol] = f2h(e);
        p += e;
      }
#pragma unroll
      for (int off = 1; off < 16; off <<= 1) p += __shfl_xor(p, off);
      if (rr == 0) atomicAdd(rs + srow, p);
    }
}

// ---------------------------------------------------------------------------
// pv: out[b,s,d] = (1/rsum[b,s]) * sum_t P[b,s,t] * vT[b,d,t]   (fp32 out)
// grid (8,16,4); K truncated to (ts+1)*128; y reversed (big-K first).
// BK=64 dbuf pipeline.
// ---------------------------------------------------------------------------
__global__ __launch_bounds__(256) void pv_gemm_kernel(
    const unsigned short* __restrict__ P, const unsigned short* __restrict__ vT,
    const float* __restrict__ rsum, float* __restrict__ out) {
  const int td = blockIdx.x, ts = 15 - blockIdx.y, b = blockIdx.z;
  __shared__ unsigned short As[2 * 128 * 64], Bs[2 * 128 * 64];

  f32x4 acc[4][4];
  gemm128_k64(P + ((size_t)(b * 2048 + ts * 128)) * 2048,
              vT + ((size_t)(b * 1024 + td * 128)) * 2048,
              2048, 2048, (ts + 1) * 128, As, Bs, acc);

  const int lane = threadIdx.x & 63, wave = threadIdx.x >> 6;
  const int wm = wave >> 1, wn = wave & 1, rr = lane & 15, qq = lane >> 4;
#pragma unroll
  for (int i = 0; i < 4; ++i) {
    int s0 = ts * 128 + wm * 64 + i * 16 + qq * 4;
    float4 r4 = *(const float4*)(rsum + b * 2048 + s0);
    float rv[4] = {__builtin_amdgcn_rcpf(r4.x), __builtin_amdgcn_rcpf(r4.y),
                   __builtin_amdgcn_rcpf(r4.z), __builtin_amdgcn_rcpf(r4.w)};
#pragma unroll
    for (int reg = 0; reg < 4; ++reg) {
      int srow = s0 + reg;
#pragma unroll
      for (int j = 0; j < 4; ++j) {
        int dcol = td * 128 + wn * 64 + j * 16 + rr;
        out[((size_t)(b * 2048 + srow)) * 1024 + dcol] =
            acc[i][j][reg] * rv[reg];
      }
    }
  }
}

// ---------------------------------------------------------------------------
// launch
// ---------------------------------------------------------------------------
extern "C" void kernel_launch(void* const* d_in, const int* in_sizes, int n_in,
                              void* d_out, int out_size, void* d_ws,
                              size_t ws_size, hipStream_t stream) {
  const float* x  = (const float*)d_in[0];
  const float* Wk = (const float*)d_in[1];
  const float* bk = (const float*)d_in[2];
  const float* Wq = (const float*)d_in[3];
  const float* bq = (const float*)d_in[4];
  const float* Wv = (const float*)d_in[5];
  const float* bv = (const float*)d_in[6];
  float* out = (float*)d_out;

  char* ws = (char*)d_ws;
  const size_t MB = 1ull << 20;
  // Aliased layout (86 MB + 32 KB): P overlays xh/wh (dead by scores).
  unsigned short* xh = (unsigned short*)(ws + 0);        // 16 MB  [0,16)
  unsigned short* wh = (unsigned short*)(ws + 16 * MB);  //  6 MB  [16,22)
  unsigned short* P  = (unsigned short*)(ws + 0);        // 32 MB  [0,32) alias
  unsigned short* kh = (unsigned short*)(ws + 38 * MB);  // 16 MB  [38,54)
  unsigned short* qh = (unsigned short*)(ws + 54 * MB);  // 16 MB  [54,70)
  unsigned short* vT = (unsigned short*)(ws + 70 * MB);  // 16 MB  [70,86)
  float* rsum = (float*)(ws + 86 * MB);                  // 32 KB

  // 1) converts (x + 3 W) + rsum zero-init (last 8 blocks)
  cvt_kernel<<<11272, 256, 0, stream>>>(x, Wk, Wq, Wv, xh, rsum);
  // 2) QKV projections, 256^2 4-buffer counted-vmcnt; V operand-swapped -> vT
  qkv256_kernel<<<384, 512, 0, stream>>>(xh, wh, bk, bq, bv, kh, qh, vT);
  // 3) masked exp(scores) + fused row-sum atomics (BK=64 dbuf)
  scores_kernel<<<dim3(136, 4), 256, 0, stream>>>(kh, qh, P, rsum);
  // 4) (P @ v) * (1/rsum) -> out (BK=64 dbuf)
  pv_gemm_kernel<<<dim3(8, 16, 4), 256, 0, stream>>>(P, vT, rsum, out);
}

// Round 5
// 241.889 us; speedup vs baseline: 1.0309x; 1.0065x over previous
//
#include <hip/hip_runtime.h>
#include <cstdint>

// ---------------------------------------------------------------------------
// DefaultAttention: x[4,2048,1024] fp32; k=xWk^T+bk, q=xWq^T+bq, v=xWv^T+bv;
// sim = k q^T / 32 (causal tril), attn = softmax(sim), out = attn @ v (fp32).
// R16: (a) qkv REVERTED to the R11 gemm128 BK=32 kernel (verified 72.5us;
// four 256^2 pipeline rewrites R12-R15 all plateaued at 72-86us).
// (b) scores/pv are now PERSISTENT blocks pulling jobs from a global atomic
// queue. Old pv grid = 512 blocks on exactly 512 co-resident slots (2/CU,
// 64KB LDS) with per-block work proportional to (ts+1) in 1..16 units ->
// slot utilization 4352/(512*32) = 27%. Queue + big-K-first (LPT) order
// packs slots (makespan ~ sum/slots). scores (544 jobs/512 slots) similarly
// loses its 32-block second generation. Math unchanged; assignment only.
// Queue counters live in the unused [36MB) workspace hole, zeroed by cvt
// each launch (stream-ordered; no hipMemset -> graph-capture-safe).
// ---------------------------------------------------------------------------

typedef __attribute__((ext_vector_type(8))) _Float16 f16x8;
typedef __attribute__((ext_vector_type(4))) float f32x4;

__device__ __forceinline__ unsigned short f2h(float x) {
  return __builtin_bit_cast(unsigned short, (_Float16)x);
}

// async global->LDS, 16B per lane; LDS dest = wave-uniform base + lane*16
__device__ __forceinline__ void lds_dma16(const void* g, void* l) {
  auto gp = reinterpret_cast<const __attribute__((address_space(1))) void*>(
      reinterpret_cast<uintptr_t>(g));
  auto lp = reinterpret_cast<__attribute__((address_space(3))) void*>(
      reinterpret_cast<uintptr_t>(l));
  __builtin_amdgcn_global_load_lds(gp, lp, 16, 0, 0);
}

// ---------------------------------------------------------------------------
// gemm128 (BK=32 dbuf, 256 thr): C[128x128] += A[128xK] * B[128xK]^T.
// XOR-swizzled LDS, double-buffered single-barrier pipeline (R4-verified).
// ---------------------------------------------------------------------------
__device__ __forceinline__ void gemm128(const unsigned short* __restrict__ Ag,
                                        const unsigned short* __restrict__ Bg,
                                        int lda, int ldb, int nk,
                                        unsigned short* As, unsigned short* Bs,
                                        f32x4 acc[4][4]) {
  const int tid = threadIdx.x;
  const int lane = tid & 63, wave = tid >> 6;
  const int wm = wave >> 1, wn = wave & 1;
  const int sr = lane >> 2;                               // staging row in chunk
  const int scb = (((lane & 3) ^ ((lane >> 3) & 3)) * 8); // swizzled src col
  const int rr = lane & 15, qq = lane >> 4;
  const int slot = ((qq ^ ((rr >> 1) & 3)) * 8);          // swizzled read col

#pragma unroll
  for (int i = 0; i < 4; ++i)
#pragma unroll
    for (int j = 0; j < 4; ++j) {
      f32x4 z = {0.f, 0.f, 0.f, 0.f};
      acc[i][j] = z;
    }

#pragma unroll
  for (int c = 0; c < 2; ++c) {
    int chunk = wave * 2 + c;
    int row = chunk * 16 + sr;
    lds_dma16(Ag + (size_t)row * lda + scb, As + chunk * 512);
    lds_dma16(Bg + (size_t)row * ldb + scb, Bs + chunk * 512);
  }

  int buf = 0;
  for (int k0 = 0; k0 < nk; k0 += 32) {
    __syncthreads();  // drains staging issued one compute-phase ago
    const int kn = k0 + 32;
    if (kn < nk) {
      unsigned short* An = As + (buf ^ 1) * 4096;
      unsigned short* Bn = Bs + (buf ^ 1) * 4096;
#pragma unroll
      for (int c = 0; c < 2; ++c) {
        int chunk = wave * 2 + c;
        int row = chunk * 16 + sr;
        lds_dma16(Ag + (size_t)row * lda + kn + scb, An + chunk * 512);
        lds_dma16(Bg + (size_t)row * ldb + kn + scb, Bn + chunk * 512);
      }
    }

    f16x8 af[4], bf[4];
    const unsigned short* Ar = As + buf * 4096 + (wm * 64 + rr) * 32 + slot;
    const unsigned short* Br = Bs + buf * 4096 + (wn * 64 + rr) * 32 + slot;
#pragma unroll
    for (int i = 0; i < 4; ++i) af[i] = *(const f16x8*)(Ar + i * 512);
#pragma unroll
    for (int j = 0; j < 4; ++j) bf[j] = *(const f16x8*)(Br + j * 512);
#pragma unroll
    for (int i = 0; i < 4; ++i)
#pragma unroll
      for (int j = 0; j < 4; ++j)
        acc[i][j] = __builtin_amdgcn_mfma_f32_16x16x32_f16(af[i], bf[j],
                                                           acc[i][j], 0, 0, 0);
    buf ^= 1;
  }
}

// NOTE on gemm128's read swizzle: staging puts src col-block (s^(r&3)) at slot
// s of row r (rows are 64B, 4 slots); readers use slot (q ^ ((rr>>1)&3)) with
// the (r>>1) variant -- this is the R4-verified pair carried through R11.
// (kept verbatim from the 239.9us R11 kernel)

// ---------------------------------------------------------------------------
// gemm128_k64 (BK=64 dbuf, 256 thr): 2x16KB stages per matrix (64 KB LDS).
// R3-verified swizzle: LDS slot s of row r holds src col-block s^(r&7);
// readers use slot (cb ^ (rr&7)). 16 iters for nk=1024 -> half the barrier
// stalls; 32 MFMA/wave between barriers.
// ---------------------------------------------------------------------------
__device__ __forceinline__ void gemm128_k64(
    const unsigned short* __restrict__ Ag, const unsigned short* __restrict__ Bg,
    int lda, int ldb, int nk, unsigned short* As, unsigned short* Bs,
    f32x4 acc[4][4]) {
  const int tid = threadIdx.x;
  const int lane = tid & 63, wave = tid >> 6;
  const int wm = wave >> 1, wn = wave & 1;
  const int sr = lane >> 3;                     // staging row within 8-row chunk
  const int scb = ((lane & 7) ^ sr) * 8;        // swizzled source col (ush)
  const int rr = lane & 15, qq = lane >> 4;
  const int slot0 = ((qq) ^ (rr & 7)) * 8;      // k-half 0 read col
  const int slot1 = ((4 + qq) ^ (rr & 7)) * 8;  // k-half 1 read col

#pragma unroll
  for (int i = 0; i < 4; ++i)
#pragma unroll
    for (int j = 0; j < 4; ++j) {
      f32x4 z = {0.f, 0.f, 0.f, 0.f};
      acc[i][j] = z;
    }

  // prologue: stage k=0 into buf 0 (16 chunks of 8 rows; wave w: 4w..4w+3)
#pragma unroll
  for (int c = 0; c < 4; ++c) {
    int chunk = wave * 4 + c;
    int row = chunk * 8 + sr;
    lds_dma16(Ag + (size_t)row * lda + scb, As + chunk * 512);
    lds_dma16(Bg + (size_t)row * ldb + scb, Bs + chunk * 512);
  }

  int buf = 0;
  for (int k0 = 0; k0 < nk; k0 += 64) {
    __syncthreads();  // drains staging issued one compute-phase ago
    const int kn = k0 + 64;
    if (kn < nk) {
      unsigned short* An = As + (buf ^ 1) * 8192;
      unsigned short* Bn = Bs + (buf ^ 1) * 8192;
#pragma unroll
      for (int c = 0; c < 4; ++c) {
        int chunk = wave * 4 + c;
        int row = chunk * 8 + sr;
        lds_dma16(Ag + (size_t)row * lda + kn + scb, An + chunk * 512);
        lds_dma16(Bg + (size_t)row * ldb + kn + scb, Bn + chunk * 512);
      }
    }

    const unsigned short* Ar = As + buf * 8192 + (wm * 64 + rr) * 64;
    const unsigned short* Br = Bs + buf * 8192 + (wn * 64 + rr) * 64;
    {
      f16x8 af[4], bf[4];
#pragma unroll
      for (int i = 0; i < 4; ++i) af[i] = *(const f16x8*)(Ar + i * 1024 + slot0);
#pragma unroll
      for (int j = 0; j < 4; ++j) bf[j] = *(const f16x8*)(Br + j * 1024 + slot0);
#pragma unroll
      for (int i = 0; i < 4; ++i)
#pragma unroll
        for (int j = 0; j < 4; ++j)
          acc[i][j] = __builtin_amdgcn_mfma_f32_16x16x32_f16(af[i], bf[j],
                                                             acc[i][j], 0, 0, 0);
    }
    {
      f16x8 af[4], bf[4];
#pragma unroll
      for (int i = 0; i < 4; ++i) af[i] = *(const f16x8*)(Ar + i * 1024 + slot1);
#pragma unroll
      for (int j = 0; j < 4; ++j) bf[j] = *(const f16x8*)(Br + j * 1024 + slot1);
#pragma unroll
      for (int i = 0; i < 4; ++i)
#pragma unroll
        for (int j = 0; j < 4; ++j)
          acc[i][j] = __builtin_amdgcn_mfma_f32_16x16x32_f16(af[i], bf[j],
                                                             acc[i][j], 0, 0, 0);
    }
    buf ^= 1;
  }
}

// ---------------------------------------------------------------------------
// fp32 -> f16 convert: x then Wk,Wq,Wv into contiguous [xh | wh];
// last 8 blocks zero rsum (8192 floats) + the two job-queue counters.
// ---------------------------------------------------------------------------
__global__ void cvt_kernel(const float* __restrict__ x,
                           const float* __restrict__ w0,
                           const float* __restrict__ w1,
                           const float* __restrict__ w2,
                           unsigned short* __restrict__ dst,
                           float* __restrict__ rsum, int* __restrict__ cnt) {
  int i = blockIdx.x * 256 + threadIdx.x;
  if (i >= 2883584) {
    int z2 = i - 2883584;
    float4 z = {0.f, 0.f, 0.f, 0.f};
    ((float4*)rsum)[z2] = z;
    if (z2 == 0) { cnt[0] = 0; cnt[1] = 0; }
    return;
  }
  const float* s;
  size_t si;
  if (i < 2097152) {
    s = x; si = i;
  } else {
    int j = i - 2097152;
    int z = j >> 18;
    s = (z == 0) ? w0 : ((z == 1) ? w1 : w2);
    si = j & 262143;
  }
  float4 f = ((const float4*)s)[si];
  ushort4 u;
  u.x = f2h(f.x); u.y = f2h(f.y); u.z = f2h(f.z); u.w = f2h(f.w);
  ((ushort4*)dst)[i] = u;
}

// ---------------------------------------------------------------------------
// QKV projection, grid (24, 64): x = z*8 + tn (z fast -> xh slab shared by
// all 24 blocks of a tm), y = tm.   [R11-verified, 72.5us]
//   z=0/1: C[t, f] = xh[t-slab] . W[f-tile]^T  -> kh/qh[t*1024 + f]
//   z=2  : C[d, t] = Wv[d-tile] . xh[t-slab]^T -> vT[b][d][t]  (direct)
// ---------------------------------------------------------------------------
__global__ __launch_bounds__(256) void qkv_gemm_kernel(
    const unsigned short* __restrict__ xh, const unsigned short* __restrict__ wh,
    const float* __restrict__ bk, const float* __restrict__ bq,
    const float* __restrict__ bv, unsigned short* __restrict__ kh,
    unsigned short* __restrict__ qh, unsigned short* __restrict__ vT) {
  __shared__ unsigned short As[2 * 128 * 32], Bs[2 * 128 * 32];
  const int tn = blockIdx.x & 7, z = blockIdx.x >> 3;
  const unsigned short* W = wh + (size_t)z * 1048576;
  const int tm = blockIdx.y;

  const unsigned short* Ag = (z == 2) ? (W + (size_t)tn * 128 * 1024)
                                      : (xh + (size_t)tm * 128 * 1024);
  const unsigned short* Bg = (z == 2) ? (xh + (size_t)tm * 128 * 1024)
                                      : (W + (size_t)tn * 128 * 1024);

  f32x4 acc[4][4];
  gemm128(Ag, Bg, 1024, 1024, 1024, As, Bs, acc);

  const int lane = threadIdx.x & 63, wave = threadIdx.x >> 6;
  const int wm = wave >> 1, wn = wave & 1, rr = lane & 15, qq = lane >> 4;

  if (z == 2) {
    // rows = d, cols = t; bias is per-row (float4 over reg)
#pragma unroll
    for (int i = 0; i < 4; ++i) {
      int d0 = tn * 128 + wm * 64 + i * 16 + qq * 4;
      float4 bi = *(const float4*)(bv + d0);
      float bir[4] = {bi.x, bi.y, bi.z, bi.w};
#pragma unroll
      for (int reg = 0; reg < 4; ++reg) {
        int d = d0 + reg;
#pragma unroll
        for (int j = 0; j < 4; ++j) {
          int tg = tm * 128 + wn * 64 + j * 16 + rr;  // global token
          int bb = tg >> 11, tt = tg & 2047;
          vT[((size_t)(bb * 1024 + d)) * 2048 + tt] =
              f2h(acc[i][j][reg] + bir[reg]);
        }
      }
    }
  } else {
    const float* bias = (z == 0) ? bk : bq;
    unsigned short* dst = (z == 0) ? kh : qh;
    float bj[4];
#pragma unroll
    for (int j = 0; j < 4; ++j)
      bj[j] = bias[tn * 128 + wn * 64 + j * 16 + rr];
#pragma unroll
    for (int i = 0; i < 4; ++i)
#pragma unroll
      for (int reg = 0; reg < 4; ++reg) {
        int gm = tm * 128 + wm * 64 + i * 16 + qq * 4 + reg;
#pragma unroll
        for (int j = 0; j < 4; ++j) {
          int gc = tn * 128 + wn * 64 + j * 16 + rr;
          dst[(size_t)gm * 1024 + gc] = f2h(acc[i][j][reg] + bj[j]);
        }
      }
  }
}

// ---------------------------------------------------------------------------
// scores (persistent): P[b,s,t] = exp(k[s].q[t]/32 - 4) for t<=s else 0 (f16)
// + fused row-sum atomics. 544 jobs via atomic queue (cnt[0]); grid 512.
// Job j: b = j/136, idx = j%136 -> triangular (ts,tt). BK=64 dbuf pipeline.
// ---------------------------------------------------------------------------
__global__ __launch_bounds__(256) void scores_kernel(
    const unsigned short* __restrict__ kh, const unsigned short* __restrict__ qh,
    unsigned short* __restrict__ P, float* __restrict__ rsum,
    int* __restrict__ cnt) {
  __shared__ unsigned short As[2 * 128 * 64], Bs[2 * 128 * 64];
  __shared__ int js;
  const int tid = threadIdx.x;

  for (;;) {
    if (tid == 0) js = atomicAdd(cnt, 1);
    __syncthreads();
    const int j = js;
    if (j >= 544) return;  // uniform: all threads read the same js

    const int b = j / 136;
    int idx = j - b * 136;
    int ts = (int)((sqrtf(8.0f * idx + 1.0f) - 1.0f) * 0.5f);
    while ((ts + 1) * (ts + 2) / 2 <= idx) ++ts;
    while (ts * (ts + 1) / 2 > idx) --ts;
    const int tt = idx - ts * (ts + 1) / 2;

    f32x4 acc[4][4];
    gemm128_k64(kh + ((size_t)(b * 2048 + ts * 128)) * 1024,
                qh + ((size_t)(b * 2048 + tt * 128)) * 1024,
                1024, 1024, 1024, As, Bs, acc);
    // gemm's internal barriers order all lanes' js-read before the next
    // iteration's js-write by thread 0.

    const int lane = tid & 63, wave = tid >> 6;
    const int wm = wave >> 1, wn = wave & 1, rr = lane & 15, qq = lane >> 4;
    unsigned short* Pb = P + (size_t)b * 2048 * 2048;
    float* rs = rsum + b * 2048;
#pragma unroll
    for (int i = 0; i < 4; ++i)
#pragma unroll
      for (int reg = 0; reg < 4; ++reg) {
        int srow = ts * 128 + wm * 64 + i * 16 + qq * 4 + reg;
        float p = 0.f;
#pragma unroll
        for (int jj = 0; jj < 4; ++jj) {
          int tcol = tt * 128 + wn * 64 + jj * 16 + rr;
          float e = (tcol <= srow) ? __expf(acc[i][jj][reg] * 0.03125f - 4.0f)
                                   : 0.0f;
          Pb[(size_t)srow * 2048 + tcol] = f2h(e);
          p += e;
        }
#pragma unroll
        for (int off = 1; off < 16; off <<= 1) p += __shfl_xor(p, off);
        if (rr == 0) atomicAdd(rs + srow, p);
      }
  }
}

// ---------------------------------------------------------------------------
// pv (persistent): out[b,s,d] = (1/rsum[b,s]) * sum_t P[b,s,t] * vT[b,d,t]
// 512 jobs via atomic queue (cnt[1]); grid 512. Job j (big-K-first / LPT):
// tsrev = j>>5, b = (j>>3)&3, td = j&7; ts = 15 - tsrev; K = (ts+1)*128.
// BK=64 dbuf pipeline.
// ---------------------------------------------------------------------------
__global__ __launch_bounds__(256) void pv_gemm_kernel(
    const unsigned short* __restrict__ P, const unsigned short* __restrict__ vT,
    const float* __restrict__ rsum, float* __restrict__ out,
    int* __restrict__ cnt) {
  __shared__ unsigned short As[2 * 128 * 64], Bs[2 * 128 * 64];
  __shared__ int js;
  const int tid = threadIdx.x;

  for (;;) {
    if (tid == 0) js = atomicAdd(cnt + 1, 1);
    __syncthreads();
    const int j = js;
    if (j >= 512) return;

    const int ts = 15 - (j >> 5), b = (j >> 3) & 3, td = j & 7;

    f32x4 acc[4][4];
    gemm128_k64(P + ((size_t)(b * 2048 + ts * 128)) * 2048,
                vT + ((size_t)(b * 1024 + td * 128)) * 2048,
                2048, 2048, (ts + 1) * 128, As, Bs, acc);

    const int lane = tid & 63, wave = tid >> 6;
    const int wm = wave >> 1, wn = wave & 1, rr = lane & 15, qq = lane >> 4;
#pragma unroll
    for (int i = 0; i < 4; ++i) {
      int s0 = ts * 128 + wm * 64 + i * 16 + qq * 4;
      float4 r4 = *(const float4*)(rsum + b * 2048 + s0);
      float rv[4] = {__builtin_amdgcn_rcpf(r4.x), __builtin_amdgcn_rcpf(r4.y),
                     __builtin_amdgcn_rcpf(r4.z), __builtin_amdgcn_rcpf(r4.w)};
#pragma unroll
      for (int reg = 0; reg < 4; ++reg) {
        int srow = s0 + reg;
#pragma unroll
        for (int jj = 0; jj < 4; ++jj) {
          int dcol = td * 128 + wn * 64 + jj * 16 + rr;
          out[((size_t)(b * 2048 + srow)) * 1024 + dcol] =
              acc[i][jj][reg] * rv[reg];
        }
      }
    }
  }
}

// ---------------------------------------------------------------------------
// launch
// ---------------------------------------------------------------------------
extern "C" void kernel_launch(void* const* d_in, const int* in_sizes, int n_in,
                              void* d_out, int out_size, void* d_ws,
                              size_t ws_size, hipStream_t stream) {
  const float* x  = (const float*)d_in[0];
  const float* Wk = (const float*)d_in[1];
  const float* bk = (const float*)d_in[2];
  const float* Wq = (const float*)d_in[3];
  const float* bq = (const float*)d_in[4];
  const float* Wv = (const float*)d_in[5];
  const float* bv = (const float*)d_in[6];
  float* out = (float*)d_out;

  char* ws = (char*)d_ws;
  const size_t MB = 1ull << 20;
  // Aliased layout (86 MB + 32 KB): P overlays xh/wh (dead by scores).
  unsigned short* xh = (unsigned short*)(ws + 0);        // 16 MB  [0,16)
  unsigned short* wh = (unsigned short*)(ws + 16 * MB);  //  6 MB  [16,22)
  unsigned short* P  = (unsigned short*)(ws + 0);        // 32 MB  [0,32) alias
  int* cnt = (int*)(ws + 36 * MB);                       // queue counters
  unsigned short* kh = (unsigned short*)(ws + 38 * MB);  // 16 MB  [38,54)
  unsigned short* qh = (unsigned short*)(ws + 54 * MB);  // 16 MB  [54,70)
  unsigned short* vT = (unsigned short*)(ws + 70 * MB);  // 16 MB  [70,86)
  float* rsum = (float*)(ws + 86 * MB);                  // 32 KB

  // 1) converts (x + 3 W) + rsum/counter zero-init (last 8 blocks)
  cvt_kernel<<<11272, 256, 0, stream>>>(x, Wk, Wq, Wv, xh, rsum, cnt);
  // 2) QKV projections (R11 gemm128); z=2 operand-swapped -> writes vT
  qkv_gemm_kernel<<<dim3(24, 64), 256, 0, stream>>>(xh, wh, bk, bq, bv,
                                                    kh, qh, vT);
  // 3) masked exp(scores) + fused row-sum atomics (persistent, queue)
  scores_kernel<<<512, 256, 0, stream>>>(kh, qh, P, rsum, cnt);
  // 4) (P @ v) * (1/rsum) -> out (persistent, queue, big-K-first)
  pv_gemm_kernel<<<512, 256, 0, stream>>>(P, vT, rsum, out, cnt);
}